// Round 11
// baseline (221.602 us; speedup 1.0000x reference)
//
#include <hip/hip_runtime.h>

typedef unsigned short ushort_t;
typedef __attribute__((ext_vector_type(8))) short short8;
typedef __attribute__((ext_vector_type(4))) float floatx4;

// ---------- helpers ----------

__device__ __forceinline__ ushort_t f2bf(float f) {
    unsigned int u = __float_as_uint(f);
    u = (u + 0x7FFFu + ((u >> 16) & 1u)) >> 16;   // round-to-nearest-even
    return (ushort_t)u;
}

typedef __attribute__((address_space(1))) void gls_g;
typedef __attribute__((address_space(3))) void gls_l;

__device__ __forceinline__ void async_copy16(const ushort_t* g, ushort_t* l) {
    __builtin_amdgcn_global_load_lds((gls_g*)g, (gls_l*)l, 16, 0, 0);
}

__device__ __forceinline__ floatx4 mfma16(short8 a, short8 b, floatx4 c) {
    return __builtin_amdgcn_mfma_f32_16x16x32_bf16(a, b, c, 0, 0, 0);
}

// ---------- fp32 -> bf16 convert: ALL tensors in ONE dispatch ----------

__global__ __launch_bounds__(256) void conv_all(const float* __restrict__ x,
                                                const float* __restrict__ wq,
                                                const float* __restrict__ wk,
                                                const float* __restrict__ wv,
                                                const float* __restrict__ wo,
                                                ushort_t* __restrict__ xb,
                                                ushort_t* __restrict__ wqkv,
                                                ushort_t* __restrict__ wob) {
    const int bid = blockIdx.x;
    const float* in;
    ushort_t* out;
    int blk;
    if (bid < 8192) { in = x; out = xb; blk = bid; }
    else {
        const int g = (bid - 8192) >> 10;
        blk = (bid - 8192) & 1023;
        in  = (g == 0) ? wq : (g == 1) ? wk : (g == 2) ? wv : wo;
        out = (g == 3) ? wob : wqkv + g * 1048576;
    }
    const int i = (blk * 256 + threadIdx.x) * 4;
    float4 f = *(const float4*)(in + i);
    ushort4 o;
    o.x = f2bf(f.x); o.y = f2bf(f.y); o.z = f2bf(f.z); o.w = f2bf(f.w);
    *(ushort4*)(out + i) = o;
}

// ---------- GEMM: C[M,N] = A[M,K] @ B[N,K]^T ----------
// 128x128 tile, BK=64, chunk^(row&7) LDS swizzle (0 conflicts).
// MODE 0: fp32 out + bias (proj). MODE 1: QKV — Q tiles (bn<8) stored bf16
// PRE-SCALED by C=(1/8)*log2(e) (folds softmax scale+log2e into Q: attn does
// exp2(s) with no per-element multiply); K tiles (8<=bn<16) unscaled; V tiles
// (bn>=16) stored DIRECTLY into vt[b*16+h][dv][s_perm] (fused transpose).
// ROUND 4 PM: 128x256/8-wave 3-buffer counted-vmcnt rewrite regressed
// 55->76.5 us — coarse 2-deep pipelining without the true 8-phase fine
// interleave hurts (m196); 144KB LDS killed multi-block implicit overlap.
// ROUND 10 PM: at this ceiling (937 TF). Any 2-buffer schedule provable
// race-free headlessly collapses to the "minimum 2-phase" recipe (682-745
// TF documented — WORSE, forfeits multi-block overlap). The true counted-
// vmcnt template needs sub-half-tile region timing that cannot be
// reconstructed+race-screened here. This kernel is final.
// ROUND 8 NOTE: 61.5 us vs 55.4 in r3/r5 with identical counters and
// proportionally lower hbm_gbps -> container clock variance, not code.

template<int MODE>
__global__ __launch_bounds__(256, 2) void gemm_nt(const ushort_t* __restrict__ A,
                                                  const ushort_t* __restrict__ B,
                                                  void* __restrict__ Cv,
                                                  const float* __restrict__ bias,
                                                  int M, int N, int K, int ldc,
                                                  ushort_t* __restrict__ vt) {
    __shared__ ushort_t lA[128 * 64];
    __shared__ ushort_t lB[128 * 64];
    const int tid  = threadIdx.x;
    const int wave = tid >> 6, lane = tid & 63;
    const int quad = lane >> 4, l15 = lane & 15;
    const int wr = (wave >> 1) * 64;
    const int wc = (wave & 1) * 64;
    const size_t bm = blockIdx.y, bn = blockIdx.x;

    const ushort_t* Ab = A + bm * 128 * (size_t)K;
    const ushort_t* Bb = B + bn * 128 * (size_t)K;

    int srow[4], scol[4];
#pragma unroll
    for (int i = 0; i < 4; ++i) {
        const int li = i * 256 + tid;
        srow[i] = li >> 3;
        scol[i] = ((li & 7) ^ (srow[i] & 7)) * 8;
    }

    floatx4 acc[4][4];
#pragma unroll
    for (int i = 0; i < 4; ++i)
#pragma unroll
        for (int j = 0; j < 4; ++j) acc[i][j] = (floatx4){0.f, 0.f, 0.f, 0.f};

    for (int kt = 0; kt < K; kt += 64) {
        __syncthreads();
#pragma unroll
        for (int i = 0; i < 4; ++i) {
            async_copy16(Ab + (size_t)srow[i] * K + kt + scol[i],
                         &lA[i * 2048] + wave * 512);
            async_copy16(Bb + (size_t)srow[i] * K + kt + scol[i],
                         &lB[i * 2048] + wave * 512);
        }
        __syncthreads();

        short8 af[4][2], bf[4][2];
#pragma unroll
        for (int mt = 0; mt < 4; ++mt)
#pragma unroll
            for (int ks = 0; ks < 2; ++ks)
                af[mt][ks] = *(const short8*)&lA[(wr + mt * 16 + l15) * 64 +
                                                 (((ks * 4 + quad) ^ (l15 & 7)) * 8)];
#pragma unroll
        for (int nt = 0; nt < 4; ++nt)
#pragma unroll
            for (int ks = 0; ks < 2; ++ks)
                bf[nt][ks] = *(const short8*)&lB[(wc + nt * 16 + l15) * 64 +
                                                 (((ks * 4 + quad) ^ (l15 & 7)) * 8)];
#pragma unroll
        for (int mt = 0; mt < 4; ++mt)
#pragma unroll
            for (int nt = 0; nt < 4; ++nt) {
                acc[mt][nt] = mfma16(af[mt][0], bf[nt][0], acc[mt][nt]);
                acc[mt][nt] = mfma16(af[mt][1], bf[nt][1], acc[mt][nt]);
            }
    }

    if (MODE == 0) {
#pragma unroll
        for (int mt = 0; mt < 4; ++mt)
#pragma unroll
            for (int nt = 0; nt < 4; ++nt)
#pragma unroll
                for (int r = 0; r < 4; ++r) {
                    const size_t m = bm * 128 + wr + mt * 16 + quad * 4 + r;
                    const size_t n = bn * 128 + wc + nt * 16 + l15;
                    ((float*)Cv)[m * (size_t)ldc + n] = acc[mt][nt][r] + bias[n];
                }
    } else if ((int)bn < 16) {                     // Q,K tiles: bf16 row-major
        const float qs = ((int)bn < 8) ? 0.18033688011112042f : 1.0f;
#pragma unroll
        for (int mt = 0; mt < 4; ++mt)
#pragma unroll
            for (int nt = 0; nt < 4; ++nt)
#pragma unroll
                for (int r = 0; r < 4; ++r) {
                    const size_t m = bm * 128 + wr + mt * 16 + quad * 4 + r;
                    const size_t n = bn * 128 + wc + nt * 16 + l15;
                    ((ushort_t*)Cv)[m * (size_t)ldc + n] = f2bf(acc[mt][nt][r] * qs);
                }
    } else {                                       // V tiles: fused transpose
        const int hh = ((int)bn - 16) * 2 + (wc >> 6);
        const int bb = (int)(bm >> 4);
        const size_t srow_off = (bm & 15) * 128 + wr;
#pragma unroll
        for (int mt = 0; mt < 4; ++mt)
#pragma unroll
            for (int nt = 0; nt < 4; ++nt) {
                ushort4 ov;
                ov.x = f2bf(acc[mt][nt][0]);
                ov.y = f2bf(acc[mt][nt][1]);
                ov.z = f2bf(acc[mt][nt][2]);
                ov.w = f2bf(acc[mt][nt][3]);
                ushort_t* dst = vt +
                    ((size_t)((bb * 16 + hh) * 64 + nt * 16 + l15)) * 2048 +
                    srow_off + (mt >> 1) * 32 + (mt & 1) * 4 + quad * 8;
                *(ushort4*)dst = ov;
            }
    }
}

// ---------- flash attention (causal), 64-key tiles ----------
// Block = 4 waves sharing 64-key K/V tiles via LDS (double-buffered, 1 barrier
// per 64 keys). Wave w owns ONE q-tile (grid 1024 = 64 bh x 16 ord,
// longest-work-first). S^T = K @ Q^T with Q PRE-SCALED by (1/8)*log2(e) ->
// p = exp2(s) directly. No online rescale; l reduced once in epilogue.
// LDS rows are 128B with chunk^(row&7) swizzle -> conflict-free.
// Diagonal by parity: even q-tile -> upper key-half fully masked; odd ->
// lower half full, upper half diagonal.
// ROUND 11: T15-style QK batching — per mt, both key-groups' QK MFMAs issue
// BEFORE either group's exp/pack, filling the ~30cy MFMA->VALU result
// latency of group0's s with group1's 4 independent QK MFMAs (m214 v36:
// compiler does NOT do this reorder itself; +7-11% there). Same math,
// same masks; +~12 live VGPR (sB pair + longer pb0 life), target <=128.
// ROUND 2 PM: (256,4) clamped VGPR to 64 -> ~222MB spill. Keep (256,2).
// ROUND 5 PM: setprio neutral-to-negative (lockstep waves). Removed.
// ROUND 6 PM: placement-model ord permutation regressed ~3us. Falsified.
// ROUND 9 PM: mirror-paired 8-wave blocks regressed 52->76.5us (barrier
// couples waves to block-max iters). Heterogeneous work stays in SEPARATE
// blocks.

__device__ __forceinline__ void qk_mfma(const short8 (&kg)[2][2],
                                        short8 qf0, short8 qf1, bool full,
                                        floatx4& s0, floatx4& s1) {
    const floatx4 z = {0.f, 0.f, 0.f, 0.f};
    s1 = z;
    s0 = mfma16(kg[0][0], qf0, z);
    s0 = mfma16(kg[0][1], qf1, s0);
    if (full) {
        s1 = mfma16(kg[1][0], qf0, z);
        s1 = mfma16(kg[1][1], qf1, s1);
    }
}

__device__ __forceinline__ short8 sm_finish(floatx4 s0, floatx4 s1, bool full,
                                            int dmask, int quad, int l15,
                                            float& lacc) {
    float p[8];
    if (!full) {                                   // diag && mt==0: sub1 all future
#pragma unroll
        for (int r = 0; r < 4; ++r) {
            p[r] = __builtin_amdgcn_exp2f(s0[r]);
            if (quad * 4 + r > l15) p[r] = 0.f;
            p[r + 4] = 0.f;
        }
    } else {
#pragma unroll
        for (int r = 0; r < 4; ++r) {
            p[r]     = __builtin_amdgcn_exp2f(s0[r]);
            p[r + 4] = __builtin_amdgcn_exp2f(s1[r]);
        }
        if (dmask) {                               // mt==1: only sub1 diagonal
#pragma unroll
            for (int r = 0; r < 4; ++r)
                if (quad * 4 + r > l15) p[r + 4] = 0.f;
        }
    }
    lacc += ((p[0] + p[1]) + (p[2] + p[3])) + ((p[4] + p[5]) + (p[6] + p[7]));
    union { unsigned u[4]; short8 s8; } pk;
#pragma unroll
    for (int j = 0; j < 4; ++j)
        pk.u[j] = __builtin_amdgcn_perm(__float_as_uint(p[2 * j + 1]),
                                        __float_as_uint(p[2 * j]), 0x07060302u);
    return pk.s8;
}

__global__ __launch_bounds__(256, 2) void attn_fwd(const ushort_t* __restrict__ qkv,
                                                   const ushort_t* __restrict__ vt,
                                                   ushort_t* __restrict__ attn) {
    __shared__ ushort_t lK[2][4096];               // [buf][64 key][64 dk] swizzled
    __shared__ ushort_t lV[2][4096];               // [buf][64 dv][64 key-perm] swizzled
    const int tid = threadIdx.x, wave = tid >> 6, lane = tid & 63;
    const int quad = lane >> 4, l15 = lane & 15;
    const int bh = blockIdx.x & 63;                // same-head blocks -> same XCD
    const int ord = blockIdx.x >> 6;               // 0..15, longest-first order
    const int b = bh >> 4, h = bh & 15;

    const ushort_t* qb = qkv + (size_t)b * 2048 * 3072 + h * 64;
    const ushort_t* kb = qb + 1024;
    const ushort_t* vb = vt + (size_t)(bh * 64) * 2048;

    const int r0 = tid >> 3;                       // rows 0..31 (instr 0)
    const int r1 = 32 + r0;                        // rows 32..63 (instr 1)
    const int c0 = ((tid & 7) ^ (r0 & 7)) * 8;     // r1&7 == r0&7 -> same col
    const int kc0 = (quad ^ (l15 & 7)) * 8;        // frag chunk, ks/half = 0
    const int kc1 = ((4 + quad) ^ (l15 & 7)) * 8;  // frag chunk, ks/half = 1

    // ord 0..7  -> mirror phase, slot=ord      (work n64 = 32,30,...,18)
    // ord 8..15 -> direct phase, slot=15-ord   (work n64 = 16,14,..., 2)
    const int phase = (ord < 8) ? 1 : 0;
    const int slot  = (ord < 8) ? ord : 15 - ord;
    const int t = phase ? 63 - (slot * 4 + wave) : slot * 4 + wave;
    const int tmaxb = phase ? 63 - slot * 4 : slot * 4 + 3;
    const int n64 = (tmaxb >> 1) + 1;              // block-uniform iter count
    const int Td = t >> 1;
    const int todd = t & 1;
    const int q0 = t * 32;

    short8 qf[2][2];
#pragma unroll
    for (int mt = 0; mt < 2; ++mt)
#pragma unroll
        for (int ks = 0; ks < 2; ++ks)
            qf[mt][ks] = *(const short8*)(qb +
                (size_t)(q0 + mt * 16 + l15) * 3072 + ks * 32 + quad * 8);

    floatx4 o[2][4];
    float l[2] = {0.f, 0.f};
#pragma unroll
    for (int mt = 0; mt < 2; ++mt)
#pragma unroll
        for (int d = 0; d < 4; ++d) o[mt][d] = (floatx4){0.f, 0.f, 0.f, 0.f};

    async_copy16(kb + (size_t)r0 * 3072 + c0, &lK[0][0]    + wave * 512);
    async_copy16(kb + (size_t)r1 * 3072 + c0, &lK[0][2048] + wave * 512);
    async_copy16(vb + (size_t)r0 * 2048 + c0, &lV[0][0]    + wave * 512);
    async_copy16(vb + (size_t)r1 * 2048 + c0, &lV[0][2048] + wave * 512);

#pragma unroll 1
    for (int T = 0; T < n64; ++T) {
        __syncthreads();                           // drains DMA for tile T
        if (T + 1 < n64) {
            const int nb = (T + 1) & 1;
            const ushort_t* kn = kb + (size_t)(T + 1) * 196608;
            const ushort_t* vn = vb + (T + 1) * 64;
            async_copy16(kn + (size_t)r0 * 3072 + c0, &lK[nb][0]    + wave * 512);
            async_copy16(kn + (size_t)r1 * 3072 + c0, &lK[nb][2048] + wave * 512);
            async_copy16(vn + (size_t)r0 * 2048 + c0, &lV[nb][0]    + wave * 512);
            async_copy16(vn + (size_t)r1 * 2048 + c0, &lV[nb][2048] + wave * 512);
        }
        if (T <= Td) {                             // wave-uniform activity mask
            const int buf = T & 1;
            const ushort_t* Kb = &lK[buf][0];
            const ushort_t* Vb = &lV[buf][0];
            const bool diagT = (T == Td);
            const bool hasG1 = (T < Td) || todd;
            const int g0m = (diagT && !todd) ? 1 : 0;
            const int g1m = (diagT && todd) ? 1 : 0;

            short8 k0[2][2], v0[4], k1[2][2], v1[4];
#pragma unroll
            for (int s = 0; s < 2; ++s) {
                k0[s][0] = *(const short8*)(Kb + (s * 16 + l15) * 64 + kc0);
                k0[s][1] = *(const short8*)(Kb + (s * 16 + l15) * 64 + kc1);
            }
#pragma unroll
            for (int d = 0; d < 4; ++d)
                v0[d] = *(const short8*)(Vb + (d * 16 + l15) * 64 + kc0);
            if (hasG1) {
#pragma unroll
                for (int s = 0; s < 2; ++s) {
                    k1[s][0] = *(const short8*)(Kb + ((2 + s) * 16 + l15) * 64 + kc0);
                    k1[s][1] = *(const short8*)(Kb + ((2 + s) * 16 + l15) * 64 + kc1);
                }
#pragma unroll
                for (int d = 0; d < 4; ++d)
                    v1[d] = *(const short8*)(Vb + (d * 16 + l15) * 64 + kc1);
            }

#pragma unroll
            for (int mt = 0; mt < 2; ++mt) {
                // T15-style: both groups' QK MFMAs first, then both softmax
                // finishes, then both PV chains.
                floatx4 sA0, sA1, sB0, sB1;
                const bool fullA = !(g0m && mt == 0);
                qk_mfma(k0, qf[mt][0], qf[mt][1], fullA, sA0, sA1);
                bool fullB = false;
                if (hasG1) {
                    fullB = !(g1m && mt == 0);
                    qk_mfma(k1, qf[mt][0], qf[mt][1], fullB, sB0, sB1);
                }
                const short8 pb0 = sm_finish(sA0, sA1, fullA, g0m, quad, l15, l[mt]);
                short8 pb1;
                if (hasG1)
                    pb1 = sm_finish(sB0, sB1, fullB, g1m, quad, l15, l[mt]);
#pragma unroll
                for (int d = 0; d < 4; ++d)
                    o[mt][d] = mfma16(v0[d], pb0, o[mt][d]);
                if (hasG1) {
#pragma unroll
                    for (int d = 0; d < 4; ++d)
                        o[mt][d] = mfma16(v1[d], pb1, o[mt][d]);
                }
            }
        }
    }

    // epilogue: reduce l across quads (once), scale, store 8B runs
#pragma unroll
    for (int mt = 0; mt < 2; ++mt) {
        float lt = l[mt];
        lt += __shfl_xor(lt, 16);
        lt += __shfl_xor(lt, 32);
        const float inv = 1.0f / lt;
        ushort_t* orow = attn + (size_t)(b * 2048 + q0 + mt * 16 + l15) * 1024 + h * 64;
#pragma unroll
        for (int d = 0; d < 4; ++d) {
            ushort4 ov;
            ov.x = f2bf(o[mt][d][0] * inv);
            ov.y = f2bf(o[mt][d][1] * inv);
            ov.z = f2bf(o[mt][d][2] * inv);
            ov.w = f2bf(o[mt][d][3] * inv);
            *(ushort4*)(orow + d * 16 + quad * 4) = ov;
        }
    }
}

// ---------- launch ----------

extern "C" void kernel_launch(void* const* d_in, const int* in_sizes, int n_in,
                              void* d_out, int out_size, void* d_ws, size_t ws_size,
                              hipStream_t stream) {
    const float* x  = (const float*)d_in[0];
    const float* wq = (const float*)d_in[1];
    const float* wk = (const float*)d_in[2];
    const float* wv = (const float*)d_in[3];
    const float* wo = (const float*)d_in[4];
    const float* bo = (const float*)d_in[5];

    char* ws = (char*)d_ws;
    ushort_t* xb   = (ushort_t*)(ws);
    ushort_t* wqkv = (ushort_t*)(ws + 16777216);
    ushort_t* wob  = (ushort_t*)(ws + 23068672);
    ushort_t* qkv  = (ushort_t*)(ws + 25165824);
    ushort_t* vtb  = (ushort_t*)(ws + 75497472);
    ushort_t* attn = xb;   // x no longer needed after QKV GEMM
    float* out = (float*)d_out;

    conv_all<<<12288, 256, 0, stream>>>(x, wq, wk, wv, wo, xb, wqkv, wob);

    gemm_nt<1><<<dim3(24, 64), 256, 0, stream>>>(xb, wqkv, qkv, nullptr,
                                                 8192, 3072, 1024, 3072, vtb);
    attn_fwd<<<1024, 256, 0, stream>>>(qkv, vtb, attn);
    gemm_nt<0><<<dim3(8, 64), 256, 0, stream>>>(attn, wob, out, bo,
                                                8192, 1024, 1024, 1024, nullptr);
}

// Round 12
// 217.852 us; speedup vs baseline: 1.0172x; 1.0172x over previous
//
#include <hip/hip_runtime.h>

typedef unsigned short ushort_t;
typedef __attribute__((ext_vector_type(8))) short short8;
typedef __attribute__((ext_vector_type(4))) float floatx4;

// ---------- helpers ----------

__device__ __forceinline__ ushort_t f2bf(float f) {
    unsigned int u = __float_as_uint(f);
    u = (u + 0x7FFFu + ((u >> 16) & 1u)) >> 16;   // round-to-nearest-even
    return (ushort_t)u;
}

typedef __attribute__((address_space(1))) void gls_g;
typedef __attribute__((address_space(3))) void gls_l;

__device__ __forceinline__ void async_copy16(const ushort_t* g, ushort_t* l) {
    __builtin_amdgcn_global_load_lds((gls_g*)g, (gls_l*)l, 16, 0, 0);
}

__device__ __forceinline__ floatx4 mfma16(short8 a, short8 b, floatx4 c) {
    return __builtin_amdgcn_mfma_f32_16x16x32_bf16(a, b, c, 0, 0, 0);
}

// ---------- fp32 -> bf16 convert: ALL tensors in ONE dispatch ----------

__global__ __launch_bounds__(256) void conv_all(const float* __restrict__ x,
                                                const float* __restrict__ wq,
                                                const float* __restrict__ wk,
                                                const float* __restrict__ wv,
                                                const float* __restrict__ wo,
                                                ushort_t* __restrict__ xb,
                                                ushort_t* __restrict__ wqkv,
                                                ushort_t* __restrict__ wob) {
    const int bid = blockIdx.x;
    const float* in;
    ushort_t* out;
    int blk;
    if (bid < 8192) { in = x; out = xb; blk = bid; }
    else {
        const int g = (bid - 8192) >> 10;
        blk = (bid - 8192) & 1023;
        in  = (g == 0) ? wq : (g == 1) ? wk : (g == 2) ? wv : wo;
        out = (g == 3) ? wob : wqkv + g * 1048576;
    }
    const int i = (blk * 256 + threadIdx.x) * 4;
    float4 f = *(const float4*)(in + i);
    ushort4 o;
    o.x = f2bf(f.x); o.y = f2bf(f.y); o.z = f2bf(f.z); o.w = f2bf(f.w);
    *(ushort4*)(out + i) = o;
}

// ---------- GEMM: C[M,N] = A[M,K] @ B[N,K]^T ----------
// 128x128 tile, BK=64, chunk^(row&7) LDS swizzle (0 conflicts).
// MODE 0: fp32 out + bias (proj). MODE 1: QKV — Q tiles (bn<8) stored bf16
// PRE-SCALED by C=(1/8)*log2(e) (folds softmax scale+log2e into Q: attn does
// exp2(s) with no per-element multiply); K tiles (8<=bn<16) unscaled; V tiles
// (bn>=16) stored DIRECTLY into vt[b*16+h][dv][s_perm] (fused transpose).
// ROUND 4 PM: 128x256/8-wave 3-buffer counted-vmcnt rewrite regressed
// 55->76.5 us — coarse 2-deep pipelining without the true 8-phase fine
// interleave hurts (m196); 144KB LDS killed multi-block implicit overlap.
// ROUND 10 PM: at this structure's ceiling (937 TF). Any 2-buffer schedule
// provable race-free headlessly collapses to the "minimum 2-phase" recipe
// (682-745 TF documented — WORSE, forfeits multi-block overlap). Final.
// ROUND 8 NOTE: 61.5 us vs 55.4 in r3/r5 with identical counters and
// proportionally lower hbm_gbps -> container clock variance, not code.

template<int MODE>
__global__ __launch_bounds__(256, 2) void gemm_nt(const ushort_t* __restrict__ A,
                                                  const ushort_t* __restrict__ B,
                                                  void* __restrict__ Cv,
                                                  const float* __restrict__ bias,
                                                  int M, int N, int K, int ldc,
                                                  ushort_t* __restrict__ vt) {
    __shared__ ushort_t lA[128 * 64];
    __shared__ ushort_t lB[128 * 64];
    const int tid  = threadIdx.x;
    const int wave = tid >> 6, lane = tid & 63;
    const int quad = lane >> 4, l15 = lane & 15;
    const int wr = (wave >> 1) * 64;
    const int wc = (wave & 1) * 64;
    const size_t bm = blockIdx.y, bn = blockIdx.x;

    const ushort_t* Ab = A + bm * 128 * (size_t)K;
    const ushort_t* Bb = B + bn * 128 * (size_t)K;

    int srow[4], scol[4];
#pragma unroll
    for (int i = 0; i < 4; ++i) {
        const int li = i * 256 + tid;
        srow[i] = li >> 3;
        scol[i] = ((li & 7) ^ (srow[i] & 7)) * 8;
    }

    floatx4 acc[4][4];
#pragma unroll
    for (int i = 0; i < 4; ++i)
#pragma unroll
        for (int j = 0; j < 4; ++j) acc[i][j] = (floatx4){0.f, 0.f, 0.f, 0.f};

    for (int kt = 0; kt < K; kt += 64) {
        __syncthreads();
#pragma unroll
        for (int i = 0; i < 4; ++i) {
            async_copy16(Ab + (size_t)srow[i] * K + kt + scol[i],
                         &lA[i * 2048] + wave * 512);
            async_copy16(Bb + (size_t)srow[i] * K + kt + scol[i],
                         &lB[i * 2048] + wave * 512);
        }
        __syncthreads();

        short8 af[4][2], bf[4][2];
#pragma unroll
        for (int mt = 0; mt < 4; ++mt)
#pragma unroll
            for (int ks = 0; ks < 2; ++ks)
                af[mt][ks] = *(const short8*)&lA[(wr + mt * 16 + l15) * 64 +
                                                 (((ks * 4 + quad) ^ (l15 & 7)) * 8)];
#pragma unroll
        for (int nt = 0; nt < 4; ++nt)
#pragma unroll
            for (int ks = 0; ks < 2; ++ks)
                bf[nt][ks] = *(const short8*)&lB[(wc + nt * 16 + l15) * 64 +
                                                 (((ks * 4 + quad) ^ (l15 & 7)) * 8)];
#pragma unroll
        for (int mt = 0; mt < 4; ++mt)
#pragma unroll
            for (int nt = 0; nt < 4; ++nt) {
                acc[mt][nt] = mfma16(af[mt][0], bf[nt][0], acc[mt][nt]);
                acc[mt][nt] = mfma16(af[mt][1], bf[nt][1], acc[mt][nt]);
            }
    }

    if (MODE == 0) {
#pragma unroll
        for (int mt = 0; mt < 4; ++mt)
#pragma unroll
            for (int nt = 0; nt < 4; ++nt)
#pragma unroll
                for (int r = 0; r < 4; ++r) {
                    const size_t m = bm * 128 + wr + mt * 16 + quad * 4 + r;
                    const size_t n = bn * 128 + wc + nt * 16 + l15;
                    ((float*)Cv)[m * (size_t)ldc + n] = acc[mt][nt][r] + bias[n];
                }
    } else if ((int)bn < 16) {                     // Q,K tiles: bf16 row-major
        const float qs = ((int)bn < 8) ? 0.18033688011112042f : 1.0f;
#pragma unroll
        for (int mt = 0; mt < 4; ++mt)
#pragma unroll
            for (int nt = 0; nt < 4; ++nt)
#pragma unroll
                for (int r = 0; r < 4; ++r) {
                    const size_t m = bm * 128 + wr + mt * 16 + quad * 4 + r;
                    const size_t n = bn * 128 + wc + nt * 16 + l15;
                    ((ushort_t*)Cv)[m * (size_t)ldc + n] = f2bf(acc[mt][nt][r] * qs);
                }
    } else {                                       // V tiles: fused transpose
        const int hh = ((int)bn - 16) * 2 + (wc >> 6);
        const int bb = (int)(bm >> 4);
        const size_t srow_off = (bm & 15) * 128 + wr;
#pragma unroll
        for (int mt = 0; mt < 4; ++mt)
#pragma unroll
            for (int nt = 0; nt < 4; ++nt) {
                ushort4 ov;
                ov.x = f2bf(acc[mt][nt][0]);
                ov.y = f2bf(acc[mt][nt][1]);
                ov.z = f2bf(acc[mt][nt][2]);
                ov.w = f2bf(acc[mt][nt][3]);
                ushort_t* dst = vt +
                    ((size_t)((bb * 16 + hh) * 64 + nt * 16 + l15)) * 2048 +
                    srow_off + (mt >> 1) * 32 + (mt & 1) * 4 + quad * 8;
                *(ushort4*)dst = ov;
            }
    }
}

// ---------- flash attention (causal), 64-key tiles ----------
// Block = 4 waves sharing 64-key K/V tiles via LDS (double-buffered, 1 barrier
// per 64 keys). Wave w owns ONE q-tile (grid 1024 = 64 bh x 16 ord,
// longest-work-first). S^T = K @ Q^T with Q PRE-SCALED by (1/8)*log2(e) ->
// p = exp2(s) directly. No online rescale; l reduced once in epilogue.
// LDS rows are 128B with chunk^(row&7) swizzle -> conflict-free.
// Diagonal by parity: even q-tile -> upper key-half fully masked; odd ->
// lower half full, upper half diagonal.
// ROUND 2 PM: (256,4) clamped VGPR to 64 -> ~222MB spill. Keep (256,2).
// ROUND 5 PM: setprio neutral-to-negative (lockstep waves). Removed.
// ROUND 6 PM: placement-model ord permutation regressed ~3us. Falsified.
// ROUND 9 PM: mirror-paired 8-wave blocks regressed 52->76.5us (barrier
// couples waves to block-max iters). Heterogeneous work stays in SEPARATE
// blocks.
// ROUND 11 PM: manual T15-style QK batching (both groups' QK MFMAs hoisted
// before both exp/pack blocks) regressed attn 51->58us: the compiler was
// ALREADY interleaving g1's independent QK MFMAs with PV(g0) from the
// natural order; the hoist serialized 16 exp2 back-to-back with no MFMA
// overlap and lengthened 4 f32x4 live ranges. 4th scheduling-tweak
// regression this session — do NOT hand-reorder this loop; the natural
// score_group order below is the measured optimum.

__device__ __forceinline__ short8 score_group(const short8 (&kg)[2][2],
                                              short8 qf0, short8 qf1,
                                              int dmask, int mt,
                                              int quad, int l15, float& lacc) {
    const floatx4 z = {0.f, 0.f, 0.f, 0.f};
    float p[8];
    floatx4 s0 = mfma16(kg[0][0], qf0, z);
    s0 = mfma16(kg[0][1], qf1, s0);
    if (dmask && mt == 0) {                        // sub1 keys all future
#pragma unroll
        for (int r = 0; r < 4; ++r) {
            p[r] = __builtin_amdgcn_exp2f(s0[r]);
            if (quad * 4 + r > l15) p[r] = 0.f;
            p[r + 4] = 0.f;
        }
    } else {
        floatx4 s1 = mfma16(kg[1][0], qf0, z);
        s1 = mfma16(kg[1][1], qf1, s1);
#pragma unroll
        for (int r = 0; r < 4; ++r) {
            p[r]     = __builtin_amdgcn_exp2f(s0[r]);
            p[r + 4] = __builtin_amdgcn_exp2f(s1[r]);
        }
        if (dmask) {                               // mt==1: only sub1 diagonal
#pragma unroll
            for (int r = 0; r < 4; ++r)
                if (quad * 4 + r > l15) p[r + 4] = 0.f;
        }
    }
    lacc += ((p[0] + p[1]) + (p[2] + p[3])) + ((p[4] + p[5]) + (p[6] + p[7]));
    union { unsigned u[4]; short8 s8; } pk;
#pragma unroll
    for (int j = 0; j < 4; ++j)
        pk.u[j] = __builtin_amdgcn_perm(__float_as_uint(p[2 * j + 1]),
                                        __float_as_uint(p[2 * j]), 0x07060302u);
    return pk.s8;
}

__global__ __launch_bounds__(256, 2) void attn_fwd(const ushort_t* __restrict__ qkv,
                                                   const ushort_t* __restrict__ vt,
                                                   ushort_t* __restrict__ attn) {
    __shared__ ushort_t lK[2][4096];               // [buf][64 key][64 dk] swizzled
    __shared__ ushort_t lV[2][4096];               // [buf][64 dv][64 key-perm] swizzled
    const int tid = threadIdx.x, wave = tid >> 6, lane = tid & 63;
    const int quad = lane >> 4, l15 = lane & 15;
    const int bh = blockIdx.x & 63;                // same-head blocks -> same XCD
    const int ord = blockIdx.x >> 6;               // 0..15, longest-first order
    const int b = bh >> 4, h = bh & 15;

    const ushort_t* qb = qkv + (size_t)b * 2048 * 3072 + h * 64;
    const ushort_t* kb = qb + 1024;
    const ushort_t* vb = vt + (size_t)(bh * 64) * 2048;

    const int r0 = tid >> 3;                       // rows 0..31 (instr 0)
    const int r1 = 32 + r0;                        // rows 32..63 (instr 1)
    const int c0 = ((tid & 7) ^ (r0 & 7)) * 8;     // r1&7 == r0&7 -> same col
    const int kc0 = (quad ^ (l15 & 7)) * 8;        // frag chunk, ks/half = 0
    const int kc1 = ((4 + quad) ^ (l15 & 7)) * 8;  // frag chunk, ks/half = 1

    // ord 0..7  -> mirror phase, slot=ord      (work n64 = 32,30,...,18)
    // ord 8..15 -> direct phase, slot=15-ord   (work n64 = 16,14,..., 2)
    const int phase = (ord < 8) ? 1 : 0;
    const int slot  = (ord < 8) ? ord : 15 - ord;
    const int t = phase ? 63 - (slot * 4 + wave) : slot * 4 + wave;
    const int tmaxb = phase ? 63 - slot * 4 : slot * 4 + 3;
    const int n64 = (tmaxb >> 1) + 1;              // block-uniform iter count
    const int Td = t >> 1;
    const int todd = t & 1;
    const int q0 = t * 32;

    short8 qf[2][2];
#pragma unroll
    for (int mt = 0; mt < 2; ++mt)
#pragma unroll
        for (int ks = 0; ks < 2; ++ks)
            qf[mt][ks] = *(const short8*)(qb +
                (size_t)(q0 + mt * 16 + l15) * 3072 + ks * 32 + quad * 8);

    floatx4 o[2][4];
    float l[2] = {0.f, 0.f};
#pragma unroll
    for (int mt = 0; mt < 2; ++mt)
#pragma unroll
        for (int d = 0; d < 4; ++d) o[mt][d] = (floatx4){0.f, 0.f, 0.f, 0.f};

    async_copy16(kb + (size_t)r0 * 3072 + c0, &lK[0][0]    + wave * 512);
    async_copy16(kb + (size_t)r1 * 3072 + c0, &lK[0][2048] + wave * 512);
    async_copy16(vb + (size_t)r0 * 2048 + c0, &lV[0][0]    + wave * 512);
    async_copy16(vb + (size_t)r1 * 2048 + c0, &lV[0][2048] + wave * 512);

#pragma unroll 1
    for (int T = 0; T < n64; ++T) {
        __syncthreads();                           // drains DMA for tile T
        if (T + 1 < n64) {
            const int nb = (T + 1) & 1;
            const ushort_t* kn = kb + (size_t)(T + 1) * 196608;
            const ushort_t* vn = vb + (T + 1) * 64;
            async_copy16(kn + (size_t)r0 * 3072 + c0, &lK[nb][0]    + wave * 512);
            async_copy16(kn + (size_t)r1 * 3072 + c0, &lK[nb][2048] + wave * 512);
            async_copy16(vn + (size_t)r0 * 2048 + c0, &lV[nb][0]    + wave * 512);
            async_copy16(vn + (size_t)r1 * 2048 + c0, &lV[nb][2048] + wave * 512);
        }
        if (T <= Td) {                             // wave-uniform activity mask
            const int buf = T & 1;
            const ushort_t* Kb = &lK[buf][0];
            const ushort_t* Vb = &lV[buf][0];
            const bool diagT = (T == Td);
            const bool hasG1 = (T < Td) || todd;
            const int g0m = (diagT && !todd) ? 1 : 0;
            const int g1m = (diagT && todd) ? 1 : 0;

            short8 k0[2][2], v0[4], k1[2][2], v1[4];
#pragma unroll
            for (int s = 0; s < 2; ++s) {
                k0[s][0] = *(const short8*)(Kb + (s * 16 + l15) * 64 + kc0);
                k0[s][1] = *(const short8*)(Kb + (s * 16 + l15) * 64 + kc1);
            }
#pragma unroll
            for (int d = 0; d < 4; ++d)
                v0[d] = *(const short8*)(Vb + (d * 16 + l15) * 64 + kc0);
            if (hasG1) {
#pragma unroll
                for (int s = 0; s < 2; ++s) {
                    k1[s][0] = *(const short8*)(Kb + ((2 + s) * 16 + l15) * 64 + kc0);
                    k1[s][1] = *(const short8*)(Kb + ((2 + s) * 16 + l15) * 64 + kc1);
                }
#pragma unroll
                for (int d = 0; d < 4; ++d)
                    v1[d] = *(const short8*)(Vb + (d * 16 + l15) * 64 + kc1);
            }

#pragma unroll
            for (int mt = 0; mt < 2; ++mt) {
                const short8 pb0 = score_group(k0, qf[mt][0], qf[mt][1],
                                               g0m, mt, quad, l15, l[mt]);
#pragma unroll
                for (int d = 0; d < 4; ++d)
                    o[mt][d] = mfma16(v0[d], pb0, o[mt][d]);
                if (hasG1) {
                    const short8 pb1 = score_group(k1, qf[mt][0], qf[mt][1],
                                                   g1m, mt, quad, l15, l[mt]);
#pragma unroll
                    for (int d = 0; d < 4; ++d)
                        o[mt][d] = mfma16(v1[d], pb1, o[mt][d]);
                }
            }
        }
    }

    // epilogue: reduce l across quads (once), scale, store 8B runs
#pragma unroll
    for (int mt = 0; mt < 2; ++mt) {
        float lt = l[mt];
        lt += __shfl_xor(lt, 16);
        lt += __shfl_xor(lt, 32);
        const float inv = 1.0f / lt;
        ushort_t* orow = attn + (size_t)(b * 2048 + q0 + mt * 16 + l15) * 1024 + h * 64;
#pragma unroll
        for (int d = 0; d < 4; ++d) {
            ushort4 ov;
            ov.x = f2bf(o[mt][d][0] * inv);
            ov.y = f2bf(o[mt][d][1] * inv);
            ov.z = f2bf(o[mt][d][2] * inv);
            ov.w = f2bf(o[mt][d][3] * inv);
            *(ushort4*)(orow + d * 16 + quad * 4) = ov;
        }
    }
}

// ---------- launch ----------

extern "C" void kernel_launch(void* const* d_in, const int* in_sizes, int n_in,
                              void* d_out, int out_size, void* d_ws, size_t ws_size,
                              hipStream_t stream) {
    const float* x  = (const float*)d_in[0];
    const float* wq = (const float*)d_in[1];
    const float* wk = (const float*)d_in[2];
    const float* wv = (const float*)d_in[3];
    const float* wo = (const float*)d_in[4];
    const float* bo = (const float*)d_in[5];

    char* ws = (char*)d_ws;
    ushort_t* xb   = (ushort_t*)(ws);
    ushort_t* wqkv = (ushort_t*)(ws + 16777216);
    ushort_t* wob  = (ushort_t*)(ws + 23068672);
    ushort_t* qkv  = (ushort_t*)(ws + 25165824);
    ushort_t* vtb  = (ushort_t*)(ws + 75497472);
    ushort_t* attn = xb;   // x no longer needed after QKV GEMM
    float* out = (float*)d_out;

    conv_all<<<12288, 256, 0, stream>>>(x, wq, wk, wv, wo, xb, wqkv, wob);

    gemm_nt<1><<<dim3(24, 64), 256, 0, stream>>>(xb, wqkv, qkv, nullptr,
                                                 8192, 3072, 1024, 3072, vtb);
    attn_fwd<<<1024, 256, 0, stream>>>(qkv, vtb, attn);
    gemm_nt<0><<<dim3(8, 64), 256, 0, stream>>>(attn, wob, out, bo,
                                                8192, 1024, 1024, 1024, nullptr);
}